// Round 1
// baseline (338.059 us; speedup 1.0000x reference)
//
#include <hip/hip_runtime.h>
#include <math.h>

// Problem constants (from reference setup_inputs)
#define NC 80            // NUM_CLASSES
constexpr int BS  = 16;      // batch
constexpr int NA  = 33600;   // anchors
constexpr int NG  = 64;      // gt boxes
constexpr int TPB = 256;
constexpr int NBLK = (NA + TPB - 1) / TPB;  // 132 blocks per batch

// insert v into descending top-3 (t0 >= t1 >= t2)
__device__ __forceinline__ void ins3(float v, float& t0, float& t1, float& t2) {
  if (v > t2) {
    if (v > t0)      { t2 = t1; t1 = t0; t0 = v; }
    else if (v > t1) { t2 = t1; t1 = v; }
    else             { t2 = v; }
  }
}

// ---------------------------------------------------------------------------
// P1: main pass. Computes IoU argmax + top3 per anchor, writes ALL outputs
// assuming no fallback (fg = best > 0.3). Block-level top3 -> workspace.
// Invalid GT boxes are zeroed in LDS so their IoU is exactly 0.0 (== ref's
// iou * valid), removing per-pair valid handling.
// ---------------------------------------------------------------------------
__global__ __launch_bounds__(TPB) void p1_kernel(
    const float4* __restrict__ pd, const float4* __restrict__ gt,
    const int* __restrict__ glab, const int* __restrict__ gmask,
    float* __restrict__ outL, float4* __restrict__ outB,
    float* __restrict__ outS, float* __restrict__ outF,
    float* __restrict__ outI, float* __restrict__ blockTop)
{
  #pragma clang fp contract(off)
  const int b   = blockIdx.y;
  const int tid = threadIdx.x;

  __shared__ float4 sbox[NG];
  __shared__ float  sarea[NG];
  __shared__ int    slab[NG];
  __shared__ int    svalid[NG];
  __shared__ float  red[TPB * 3];

  if (tid < NG) {
    int v = gmask[b * NG + tid];
    float4 g = gt[b * NG + tid];
    if (!v) g = make_float4(0.f, 0.f, 0.f, 0.f);  // zero-box => iou == 0
    sbox[tid]   = g;
    sarea[tid]  = (g.z - g.x) * (g.w - g.y);
    slab[tid]   = glab[b * NG + tid];
    svalid[tid] = v;
  }
  __syncthreads();

  const int a0 = blockIdx.x * TPB;
  const int a  = a0 + tid;
  const bool inb = a < NA;

  float t0 = -INFINITY, t1 = -INFINITY, t2 = -INFINITY;
  float best = -1.f;
  int   bidx = 0;
  bool  maskv = false;
  int   blab  = 0;

  if (inb) {
    float4 p  = pd[(long)b * NA + a];
    float  a2 = (p.z - p.x) * (p.w - p.y);
    #pragma unroll 4
    for (int g = 0; g < NG; ++g) {
      float4 gb = sbox[g];
      float iw = fminf(gb.z, p.z) - fmaxf(gb.x, p.x);
      float ih = fminf(gb.w, p.w) - fmaxf(gb.y, p.y);
      iw = fmaxf(iw, 0.f);
      ih = fmaxf(ih, 0.f);
      float inter = iw * ih;
      float den   = sarea[g] + a2 - inter + 1e-9f;
      float iou   = inter / den;                 // IEEE divide, matches np
      if (iou > best) { best = iou; bidx = g; }  // first-index tie-break
      ins3(iou, t0, t1, t2);
    }
    bool fg = best > 0.3f;
    maskv = fg && (svalid[bidx] != 0);
    blab  = slab[bidx];
    long ga = (long)b * NA + a;
    outL[ga] = maskv ? (float)blab : 80.f;       // BG_IDX = 80
    float m = maskv ? 1.f : 0.f;
    float4 gb = sbox[bidx];
    outB[ga] = make_float4(gb.x * m, gb.y * m, gb.z * m, gb.w * m);
    outF[ga] = fg ? 1.f : 0.f;
    outI[ga] = (float)bidx;
  }

  // ---- block top3 reduction -> workspace ----
  red[tid * 3 + 0] = t0; red[tid * 3 + 1] = t1; red[tid * 3 + 2] = t2;
  __syncthreads();
  for (int s = TPB / 2; s > 0; s >>= 1) {
    if (tid < s) {
      ins3(red[(tid + s) * 3 + 0], t0, t1, t2);
      ins3(red[(tid + s) * 3 + 1], t0, t1, t2);
      ins3(red[(tid + s) * 3 + 2], t0, t1, t2);
      red[tid * 3 + 0] = t0; red[tid * 3 + 1] = t1; red[tid * 3 + 2] = t2;
    }
    __syncthreads();
  }
  if (tid == 0) {
    float* bt = blockTop + ((long)b * gridDim.x + blockIdx.x) * 3;
    bt[0] = t0; bt[1] = t1; bt[2] = t2;
  }

  // ---- scores: coalesced zero-fill of this block's 80-wide rows ----
  const int nA = min(TPB, NA - a0);
  float4* s4 = (float4*)(outS + ((long)b * NA + a0) * NC);
  const int cnt4 = nA * (NC / 4);
  for (int i = tid; i < cnt4; i += TPB) s4[i] = make_float4(0.f, 0.f, 0.f, 0.f);
  __syncthreads();
  if (inb && maskv) outS[((long)b * NA + a) * NC + blab] = 1.f;
}

// ---------------------------------------------------------------------------
// P2: per-batch merge of block top3s -> min_iou (3rd largest) and need_fb.
// fg_any == (global top1 > 0.3).
// ---------------------------------------------------------------------------
__global__ __launch_bounds__(TPB) void p2_kernel(
    const float* __restrict__ blockTop, const int* __restrict__ gmask,
    float* __restrict__ batchMin, int* __restrict__ batchFb)
{
  const int b   = blockIdx.x;
  const int tid = threadIdx.x;
  __shared__ float red[TPB * 3];
  __shared__ int   sv;
  if (tid == 0) sv = 0;
  __syncthreads();

  float t0 = -INFINITY, t1 = -INFINITY, t2 = -INFINITY;
  for (int i = tid; i < NBLK; i += TPB) {
    const float* bt = blockTop + ((long)b * NBLK + i) * 3;
    ins3(bt[0], t0, t1, t2);
    ins3(bt[1], t0, t1, t2);
    ins3(bt[2], t0, t1, t2);
  }
  if (tid < NG && gmask[b * NG + tid] != 0) atomicOr(&sv, 1);

  red[tid * 3 + 0] = t0; red[tid * 3 + 1] = t1; red[tid * 3 + 2] = t2;
  __syncthreads();
  for (int s = TPB / 2; s > 0; s >>= 1) {
    if (tid < s) {
      ins3(red[(tid + s) * 3 + 0], t0, t1, t2);
      ins3(red[(tid + s) * 3 + 1], t0, t1, t2);
      ins3(red[(tid + s) * 3 + 2], t0, t1, t2);
      red[tid * 3 + 0] = t0; red[tid * 3 + 1] = t1; red[tid * 3 + 2] = t2;
    }
    __syncthreads();
  }
  if (tid == 0) {
    batchMin[b] = t2;
    batchFb[b]  = (!(t0 > 0.3f) && (sv != 0)) ? 1 : 0;
  }
}

// ---------------------------------------------------------------------------
// P3: fallback fixup. Exits immediately unless need_fb[b]. Since need_fb
// implies P1 wrote that batch entirely as background (fg all false, scores
// all zero), we only rewrite per-anchor outputs + scatter new ones.
// target_gt_idx is fallback-independent -> not rewritten.
// ---------------------------------------------------------------------------
__global__ __launch_bounds__(TPB) void p3_kernel(
    const float4* __restrict__ pd, const float4* __restrict__ gt,
    const int* __restrict__ glab, const int* __restrict__ gmask,
    const float* __restrict__ batchMin, const int* __restrict__ batchFb,
    float* __restrict__ outL, float4* __restrict__ outB,
    float* __restrict__ outS, float* __restrict__ outF)
{
  #pragma clang fp contract(off)
  const int b = blockIdx.y;
  if (batchFb[b] == 0) return;  // uniform exit, before any __syncthreads
  const float minio = batchMin[b];
  const int tid = threadIdx.x;

  __shared__ float4 sbox[NG];
  __shared__ float  sarea[NG];
  __shared__ int    slab[NG];
  __shared__ int    svalid[NG];
  if (tid < NG) {
    int v = gmask[b * NG + tid];
    float4 g = gt[b * NG + tid];
    if (!v) g = make_float4(0.f, 0.f, 0.f, 0.f);
    sbox[tid]   = g;
    sarea[tid]  = (g.z - g.x) * (g.w - g.y);
    slab[tid]   = glab[b * NG + tid];
    svalid[tid] = v;
  }
  __syncthreads();

  const int a = blockIdx.x * TPB + tid;
  if (a >= NA) return;

  float4 p  = pd[(long)b * NA + a];
  float  a2 = (p.z - p.x) * (p.w - p.y);
  float best = -1.f;
  int   bidx = 0;
  #pragma unroll 4
  for (int g = 0; g < NG; ++g) {
    float4 gb = sbox[g];
    float iw = fminf(gb.z, p.z) - fmaxf(gb.x, p.x);
    float ih = fminf(gb.w, p.w) - fmaxf(gb.y, p.y);
    iw = fmaxf(iw, 0.f);
    ih = fmaxf(ih, 0.f);
    float inter = iw * ih;
    float den   = sarea[g] + a2 - inter + 1e-9f;
    float iou   = inter / den;
    if (iou > best) { best = iou; bidx = g; }
  }
  // fallback fg: max over valid of overlaps >= min_iou. With zero-boxes and
  // has_valid guaranteed here, max over all g == max over valid g.
  bool fg    = best >= minio;
  bool maskv = fg && (svalid[bidx] != 0);
  int  blab  = slab[bidx];
  long ga = (long)b * NA + a;
  outL[ga] = maskv ? (float)blab : 80.f;
  float m = maskv ? 1.f : 0.f;
  float4 gb = sbox[bidx];
  outB[ga] = make_float4(gb.x * m, gb.y * m, gb.z * m, gb.w * m);
  outF[ga] = fg ? 1.f : 0.f;
  if (maskv) outS[ga * NC + blab] = 1.f;  // scores were all-zero for this batch
}

// ---------------------------------------------------------------------------
// launch
// ---------------------------------------------------------------------------
extern "C" void kernel_launch(void* const* d_in, const int* in_sizes, int n_in,
                              void* d_out, int out_size, void* d_ws, size_t ws_size,
                              hipStream_t stream) {
  // inputs (setup_inputs order): 0 pd_scores (unused), 1 pd_bboxes,
  // 2 anc_points (unused), 3 gt_labels, 4 gt_bboxes, 5 mask_gt
  const float4* pd    = (const float4*)d_in[1];
  const int*    glab  = (const int*)d_in[3];
  const float4* gt    = (const float4*)d_in[4];
  const int*    gmask = (const int*)d_in[5];

  float* outf = (float*)d_out;
  // outputs concatenated flat in return order (all as float32):
  // target_labels [16,33600], target_bboxes [16,33600,4],
  // target_scores [16,33600,80], fg_mask [16,33600], target_gt_idx [16,33600]
  float*  outL = outf;
  float4* outB = (float4*)(outf + (long)BS * NA);
  float*  outS = outf + (long)BS * NA * 5;
  float*  outF = outf + (long)BS * NA * 5 + (long)BS * NA * NC;
  float*  outI = outF + (long)BS * NA;

  // workspace: block top3 (BS*NBLK*3 floats) + batchMin (BS) + batchFb (BS)
  float* blockTop = (float*)d_ws;
  float* batchMin = blockTop + (long)BS * NBLK * 3;
  int*   batchFb  = (int*)(batchMin + BS);

  dim3 grid(NBLK, BS);
  p1_kernel<<<grid, TPB, 0, stream>>>(pd, gt, glab, gmask,
                                      outL, outB, outS, outF, outI, blockTop);
  p2_kernel<<<BS, TPB, 0, stream>>>(blockTop, gmask, batchMin, batchFb);
  p3_kernel<<<grid, TPB, 0, stream>>>(pd, gt, glab, gmask, batchMin, batchFb,
                                      outL, outB, outS, outF);
}

// Round 2
// 302.010 us; speedup vs baseline: 1.1194x; 1.1194x over previous
//
#include <hip/hip_runtime.h>
#include <math.h>

// Problem constants (from reference setup_inputs)
#define NC 80            // NUM_CLASSES
constexpr int BS  = 16;      // batch
constexpr int NA  = 33600;   // anchors
constexpr int NG  = 64;      // gt boxes
constexpr int TPB = 256;
constexpr int NBLK = (NA + TPB - 1) / TPB;  // 132 blocks per batch

// branchless insert of v into descending top-3 (t0 >= t1 >= t2): 6 VALU ops
__device__ __forceinline__ void ins3(float v, float& t0, float& t1, float& t2) {
  t2 = fmaxf(t2, fminf(v, t1));   // uses old t1
  t1 = fmaxf(t1, fminf(v, t0));   // uses old t0
  t0 = fmaxf(t0, v);
}

// ---------------------------------------------------------------------------
// P1: main pass. Zero-fill of the 80-wide score rows is issued FIRST so the
// 172 MB of streaming stores drain through HBM while the VALU computes IoUs.
// Exact IEEE divide is kept so all comparisons (0.3 threshold, argmax, top3)
// match numpy bit-for-bit. Invalid GT boxes are zeroed in LDS so their IoU is
// exactly 0.0 (== ref's iou * valid). One barrier for LDS staging, one for
// the cross-wave top3 merge (which also fences fill-stores vs one-hot scatter).
// ---------------------------------------------------------------------------
__global__ __launch_bounds__(TPB) void p1_kernel(
    const float4* __restrict__ pd, const float4* __restrict__ gt,
    const int* __restrict__ glab, const int* __restrict__ gmask,
    float* __restrict__ outL, float4* __restrict__ outB,
    float* __restrict__ outS, float* __restrict__ outF,
    float* __restrict__ outI, float* __restrict__ blockTop)
{
  #pragma clang fp contract(off)
  const int b   = blockIdx.y;
  const int tid = threadIdx.x;

  __shared__ float4 sbox[NG];
  __shared__ float  sarea[NG];
  __shared__ int    slab[NG];
  __shared__ int    svalid[NG];
  __shared__ float  swt[4][3];   // per-wave top3

  const int a0  = blockIdx.x * TPB;
  const int a   = a0 + tid;
  const bool inb = a < NA;

  // ---- 1) streaming zero-fill of this block's score rows (no deps) ----
  const int nA = min(TPB, NA - a0);
  float4* s4 = (float4*)(outS + ((long)b * NA + a0) * NC);
  const int cnt4 = nA * (NC / 4);
  for (int i = tid; i < cnt4; i += TPB) s4[i] = make_float4(0.f, 0.f, 0.f, 0.f);

  // ---- 2) own pd box (issued before the barrier) ----
  float4 p = make_float4(0.f, 0.f, 0.f, 0.f);
  if (inb) p = pd[(long)b * NA + a];

  // ---- 3) stage gt into LDS ----
  if (tid < NG) {
    int v = gmask[b * NG + tid];
    float4 g = gt[b * NG + tid];
    if (!v) g = make_float4(0.f, 0.f, 0.f, 0.f);  // zero-box => iou == 0
    sbox[tid]   = g;
    sarea[tid]  = (g.z - g.x) * (g.w - g.y);
    slab[tid]   = glab[b * NG + tid];
    svalid[tid] = v;
  }
  __syncthreads();

  float t0 = -INFINITY, t1 = -INFINITY, t2 = -INFINITY;
  float best = -1.f;
  int   bidx = 0;
  bool  maskv = false;
  int   blab  = 0;

  if (inb) {
    const float a2 = (p.z - p.x) * (p.w - p.y);
    #pragma unroll 4
    for (int g = 0; g < NG; ++g) {
      float4 gb = sbox[g];
      float iw = fminf(gb.z, p.z) - fmaxf(gb.x, p.x);
      float ih = fminf(gb.w, p.w) - fmaxf(gb.y, p.y);
      iw = fmaxf(iw, 0.f);
      ih = fmaxf(ih, 0.f);
      float inter = iw * ih;
      float den   = sarea[g] + a2 - inter + 1e-9f;
      float iou   = inter / den;                 // exact IEEE, matches np
      bidx = (iou > best) ? g : bidx;            // first-index tie-break
      best = fmaxf(best, iou);
      ins3(iou, t0, t1, t2);
    }
    bool fg = best > 0.3f;
    maskv = fg && (svalid[bidx] != 0);
    blab  = slab[bidx];
    long ga = (long)b * NA + a;
    outL[ga] = maskv ? (float)blab : 80.f;       // BG_IDX = 80
    float m = maskv ? 1.f : 0.f;
    float4 gb = sbox[bidx];
    outB[ga] = make_float4(gb.x * m, gb.y * m, gb.z * m, gb.w * m);
    outF[ga] = fg ? 1.f : 0.f;
    outI[ga] = (float)bidx;
  }

  // ---- 4) top3 reduce: 64-lane butterfly, then 4-wave merge (1 barrier) ----
  #pragma unroll
  for (int off = 32; off > 0; off >>= 1) {
    float u0 = __shfl_xor(t0, off, 64);
    float u1 = __shfl_xor(t1, off, 64);
    float u2 = __shfl_xor(t2, off, 64);
    ins3(u0, t0, t1, t2);
    ins3(u1, t0, t1, t2);
    ins3(u2, t0, t1, t2);
  }
  const int lane = tid & 63, wid = tid >> 6;
  if (lane == 0) { swt[wid][0] = t0; swt[wid][1] = t1; swt[wid][2] = t2; }
  __syncthreads();   // also fences the zero-fill stores vs the scatter below
  if (tid == 0) {
    float r0 = swt[0][0], r1 = swt[0][1], r2 = swt[0][2];
    #pragma unroll
    for (int w = 1; w < 4; ++w) {
      ins3(swt[w][0], r0, r1, r2);
      ins3(swt[w][1], r0, r1, r2);
      ins3(swt[w][2], r0, r1, r2);
    }
    float* bt = blockTop + ((long)b * gridDim.x + blockIdx.x) * 3;
    bt[0] = r0; bt[1] = r1; bt[2] = r2;
  }

  // ---- 5) one-hot scatter (own row; zero-fill is fenced by the barrier) ----
  if (inb && maskv) outS[((long)b * NA + a) * NC + blab] = 1.f;
}

// ---------------------------------------------------------------------------
// P2: per-batch merge of block top3s -> min_iou (3rd largest) and need_fb.
// fg_any == (global top1 > 0.3).
// ---------------------------------------------------------------------------
__global__ __launch_bounds__(TPB) void p2_kernel(
    const float* __restrict__ blockTop, const int* __restrict__ gmask,
    float* __restrict__ batchMin, int* __restrict__ batchFb)
{
  const int b   = blockIdx.x;
  const int tid = threadIdx.x;
  __shared__ float swt[4][3];
  __shared__ int   sv;
  if (tid == 0) sv = 0;
  __syncthreads();

  float t0 = -INFINITY, t1 = -INFINITY, t2 = -INFINITY;
  for (int i = tid; i < NBLK; i += TPB) {
    const float* bt = blockTop + ((long)b * NBLK + i) * 3;
    ins3(bt[0], t0, t1, t2);
    ins3(bt[1], t0, t1, t2);
    ins3(bt[2], t0, t1, t2);
  }
  if (tid < NG && gmask[b * NG + tid] != 0) atomicOr(&sv, 1);

  #pragma unroll
  for (int off = 32; off > 0; off >>= 1) {
    float u0 = __shfl_xor(t0, off, 64);
    float u1 = __shfl_xor(t1, off, 64);
    float u2 = __shfl_xor(t2, off, 64);
    ins3(u0, t0, t1, t2);
    ins3(u1, t0, t1, t2);
    ins3(u2, t0, t1, t2);
  }
  const int lane = tid & 63, wid = tid >> 6;
  if (lane == 0) { swt[wid][0] = t0; swt[wid][1] = t1; swt[wid][2] = t2; }
  __syncthreads();
  if (tid == 0) {
    float r0 = swt[0][0], r1 = swt[0][1], r2 = swt[0][2];
    #pragma unroll
    for (int w = 1; w < 4; ++w) {
      ins3(swt[w][0], r0, r1, r2);
      ins3(swt[w][1], r0, r1, r2);
      ins3(swt[w][2], r0, r1, r2);
    }
    batchMin[b] = r2;
    batchFb[b]  = (!(r0 > 0.3f) && (sv != 0)) ? 1 : 0;
  }
}

// ---------------------------------------------------------------------------
// P3: fallback fixup. Exits immediately unless need_fb[b]. need_fb implies P1
// wrote that batch entirely as background (fg all false, scores all zero), so
// we only rewrite per-anchor outputs + scatter new one-hots.
// target_gt_idx is fallback-independent -> not rewritten.
// ---------------------------------------------------------------------------
__global__ __launch_bounds__(TPB) void p3_kernel(
    const float4* __restrict__ pd, const float4* __restrict__ gt,
    const int* __restrict__ glab, const int* __restrict__ gmask,
    const float* __restrict__ batchMin, const int* __restrict__ batchFb,
    float* __restrict__ outL, float4* __restrict__ outB,
    float* __restrict__ outS, float* __restrict__ outF)
{
  #pragma clang fp contract(off)
  const int b = blockIdx.y;
  if (batchFb[b] == 0) return;  // uniform exit, before any __syncthreads
  const float minio = batchMin[b];
  const int tid = threadIdx.x;

  __shared__ float4 sbox[NG];
  __shared__ float  sarea[NG];
  __shared__ int    slab[NG];
  __shared__ int    svalid[NG];
  if (tid < NG) {
    int v = gmask[b * NG + tid];
    float4 g = gt[b * NG + tid];
    if (!v) g = make_float4(0.f, 0.f, 0.f, 0.f);
    sbox[tid]   = g;
    sarea[tid]  = (g.z - g.x) * (g.w - g.y);
    slab[tid]   = glab[b * NG + tid];
    svalid[tid] = v;
  }
  __syncthreads();

  const int a = blockIdx.x * TPB + tid;
  if (a >= NA) return;

  float4 p  = pd[(long)b * NA + a];
  float  a2 = (p.z - p.x) * (p.w - p.y);
  float best = -1.f;
  int   bidx = 0;
  #pragma unroll 4
  for (int g = 0; g < NG; ++g) {
    float4 gb = sbox[g];
    float iw = fminf(gb.z, p.z) - fmaxf(gb.x, p.x);
    float ih = fminf(gb.w, p.w) - fmaxf(gb.y, p.y);
    iw = fmaxf(iw, 0.f);
    ih = fmaxf(ih, 0.f);
    float inter = iw * ih;
    float den   = sarea[g] + a2 - inter + 1e-9f;
    float iou   = inter / den;
    bidx = (iou > best) ? g : bidx;
    best = fmaxf(best, iou);
  }
  // fallback fg: max over valid of overlaps >= min_iou. With zero-boxes and
  // has_valid guaranteed here, max over all g == max over valid g.
  bool fg    = best >= minio;
  bool maskv = fg && (svalid[bidx] != 0);
  int  blab  = slab[bidx];
  long ga = (long)b * NA + a;
  outL[ga] = maskv ? (float)blab : 80.f;
  float m = maskv ? 1.f : 0.f;
  float4 gb = sbox[bidx];
  outB[ga] = make_float4(gb.x * m, gb.y * m, gb.z * m, gb.w * m);
  outF[ga] = fg ? 1.f : 0.f;
  if (maskv) outS[ga * NC + blab] = 1.f;  // scores were all-zero for this batch
}

// ---------------------------------------------------------------------------
// launch
// ---------------------------------------------------------------------------
extern "C" void kernel_launch(void* const* d_in, const int* in_sizes, int n_in,
                              void* d_out, int out_size, void* d_ws, size_t ws_size,
                              hipStream_t stream) {
  // inputs (setup_inputs order): 0 pd_scores (unused), 1 pd_bboxes,
  // 2 anc_points (unused), 3 gt_labels, 4 gt_bboxes, 5 mask_gt
  const float4* pd    = (const float4*)d_in[1];
  const int*    glab  = (const int*)d_in[3];
  const float4* gt    = (const float4*)d_in[4];
  const int*    gmask = (const int*)d_in[5];

  float* outf = (float*)d_out;
  // outputs concatenated flat in return order (all as float32):
  // target_labels [16,33600], target_bboxes [16,33600,4],
  // target_scores [16,33600,80], fg_mask [16,33600], target_gt_idx [16,33600]
  float*  outL = outf;
  float4* outB = (float4*)(outf + (long)BS * NA);
  float*  outS = outf + (long)BS * NA * 5;
  float*  outF = outf + (long)BS * NA * 5 + (long)BS * NA * NC;
  float*  outI = outF + (long)BS * NA;

  // workspace: block top3 (BS*NBLK*3 floats) + batchMin (BS) + batchFb (BS)
  float* blockTop = (float*)d_ws;
  float* batchMin = blockTop + (long)BS * NBLK * 3;
  int*   batchFb  = (int*)(batchMin + BS);

  dim3 grid(NBLK, BS);
  p1_kernel<<<grid, TPB, 0, stream>>>(pd, gt, glab, gmask,
                                      outL, outB, outS, outF, outI, blockTop);
  p2_kernel<<<BS, TPB, 0, stream>>>(blockTop, gmask, batchMin, batchFb);
  p3_kernel<<<grid, TPB, 0, stream>>>(pd, gt, glab, gmask, batchMin, batchFb,
                                      outL, outB, outS, outF);
}

// Round 3
// 297.940 us; speedup vs baseline: 1.1347x; 1.0137x over previous
//
#include <hip/hip_runtime.h>
#include <math.h>

// Problem constants (from reference setup_inputs)
#define NC 80            // NUM_CLASSES
constexpr int BS  = 16;      // batch
constexpr int NA  = 33600;   // anchors
constexpr int NG  = 64;      // gt boxes
constexpr int TPB = 256;
constexpr int NBLK = (NA + TPB - 1) / TPB;  // 132 blocks per batch
constexpr int NW   = TPB / 64;              // 4 waves per block

// branchless insert of v into descending top-3 (t0 >= t1 >= t2): 6 VALU ops
__device__ __forceinline__ void ins3(float v, float& t0, float& t1, float& t2) {
  t2 = fmaxf(t2, fminf(v, t1));   // uses old t1
  t1 = fmaxf(t1, fminf(v, t0));   // uses old t0
  t0 = fmaxf(t0, v);
}

// 64-lane butterfly top3 merge
__device__ __forceinline__ void wave_top3(float& t0, float& t1, float& t2) {
  #pragma unroll
  for (int off = 32; off > 0; off >>= 1) {
    float u0 = __shfl_xor(t0, off, 64);
    float u1 = __shfl_xor(t1, off, 64);
    float u2 = __shfl_xor(t2, off, 64);
    ins3(u0, t0, t1, t2);
    ins3(u1, t0, t1, t2);
    ins3(u2, t0, t1, t2);
  }
}

// ---------------------------------------------------------------------------
// P1: main pass. Order: stage LDS -> barrier -> issue zero-fill stores (drain
// overlaps the IoU loop; only barrier #2 waits on them) -> IoU loop -> wave
// top3 butterfly -> barrier #2 (fences fill vs one-hot scatter) -> scatter +
// per-wave blockTop write. Exact IEEE divide keeps every comparison (0.3
// threshold, argmax, top3) bit-identical to numpy. Invalid GT boxes are
// zeroed in LDS so their IoU is exactly 0.0 (== ref's iou * valid).
// ---------------------------------------------------------------------------
__global__ __launch_bounds__(TPB) void p1_kernel(
    const float4* __restrict__ pd, const float4* __restrict__ gt,
    const int* __restrict__ glab, const int* __restrict__ gmask,
    float* __restrict__ outL, float4* __restrict__ outB,
    float* __restrict__ outS, float* __restrict__ outF,
    float* __restrict__ outI, float* __restrict__ blockTop)
{
  #pragma clang fp contract(off)
  const int b   = blockIdx.y;
  const int tid = threadIdx.x;

  __shared__ float4 sbox[NG];
  __shared__ float  sarea[NG];
  __shared__ int    slab[NG];
  __shared__ int    svalid[NG];

  const int a0  = blockIdx.x * TPB;
  const int a   = a0 + tid;
  const bool inb = a < NA;

  // ---- own pd box (issued before the barrier) ----
  float4 p = make_float4(0.f, 0.f, 0.f, 0.f);
  if (inb) p = pd[(long)b * NA + a];

  // ---- stage gt into LDS ----
  if (tid < NG) {
    int v = gmask[b * NG + tid];
    float4 g = gt[b * NG + tid];
    if (!v) g = make_float4(0.f, 0.f, 0.f, 0.f);  // zero-box => iou == 0
    sbox[tid]   = g;
    sarea[tid]  = (g.z - g.x) * (g.w - g.y);
    slab[tid]   = glab[b * NG + tid];
    svalid[tid] = v;
  }
  __syncthreads();

  // ---- streaming zero-fill of this block's score rows: issued AFTER the
  // barrier so the stores drain while the IoU loop runs (only barrier #2
  // waits on vmcnt(0)) ----
  const int nA = min(TPB, NA - a0);
  float4* s4 = (float4*)(outS + ((long)b * NA + a0) * NC);
  const int cnt4 = nA * (NC / 4);
  for (int i = tid; i < cnt4; i += TPB) s4[i] = make_float4(0.f, 0.f, 0.f, 0.f);

  float t0 = -INFINITY, t1 = -INFINITY, t2 = -INFINITY;
  float best = -1.f;
  int   bidx = 0;
  bool  maskv = false;
  int   blab  = 0;

  if (inb) {
    const float a2 = (p.z - p.x) * (p.w - p.y);
    #pragma unroll 8
    for (int g = 0; g < NG; ++g) {
      float4 gb = sbox[g];
      float iw = fminf(gb.z, p.z) - fmaxf(gb.x, p.x);
      float ih = fminf(gb.w, p.w) - fmaxf(gb.y, p.y);
      iw = fmaxf(iw, 0.f);
      ih = fmaxf(ih, 0.f);
      float inter = iw * ih;
      float den   = sarea[g] + a2 - inter + 1e-9f;
      float iou   = inter / den;                 // exact IEEE, matches np
      bidx = (iou > best) ? g : bidx;            // first-index tie-break
      best = fmaxf(best, iou);
      ins3(iou, t0, t1, t2);
    }
    bool fg = best > 0.3f;
    maskv = fg && (svalid[bidx] != 0);
    blab  = slab[bidx];
    long ga = (long)b * NA + a;
    outL[ga] = maskv ? (float)blab : 80.f;       // BG_IDX = 80
    float m = maskv ? 1.f : 0.f;
    float4 gb = sbox[bidx];
    outB[ga] = make_float4(gb.x * m, gb.y * m, gb.z * m, gb.w * m);
    outF[ga] = fg ? 1.f : 0.f;
    outI[ga] = (float)bidx;
  }

  // ---- per-wave top3 butterfly; lane0 of each wave writes its triple ----
  wave_top3(t0, t1, t2);

  __syncthreads();   // fences the zero-fill stores vs the scatter below

  const int lane = tid & 63, wid = tid >> 6;
  if (lane == 0) {
    float* bt = blockTop + (((long)b * NBLK + blockIdx.x) * NW + wid) * 3;
    bt[0] = t0; bt[1] = t1; bt[2] = t2;
  }

  // ---- one-hot scatter (own row; zero-fill is fenced by the barrier) ----
  if (inb && maskv) outS[((long)b * NA + a) * NC + blab] = 1.f;
}

// ---------------------------------------------------------------------------
// P3: fallback fixup (p2 folded in). Each block redundantly reduces the
// batch's per-wave blockTop triples (L2-hot, ~6 KB) + ballot over gmask to
// get min_iou / need_fb, then exits uniformly unless need_fb[b]. need_fb
// implies P1 wrote that batch entirely as background (fg all false, scores
// all zero), so only per-anchor rewrites + one-hot scatters are needed.
// target_gt_idx is fallback-independent -> not rewritten.
// ---------------------------------------------------------------------------
__global__ __launch_bounds__(TPB) void p3_kernel(
    const float4* __restrict__ pd, const float4* __restrict__ gt,
    const int* __restrict__ glab, const int* __restrict__ gmask,
    const float* __restrict__ blockTop,
    float* __restrict__ outL, float4* __restrict__ outB,
    float* __restrict__ outS, float* __restrict__ outF)
{
  #pragma clang fp contract(off)
  const int b   = blockIdx.y;
  const int tid = threadIdx.x;

  __shared__ float  swt[NW][3];
  __shared__ float  sres;      // min_iou, or NaN-coded "no fallback"
  __shared__ int    sfb;
  __shared__ float4 sbox[NG];
  __shared__ float  sarea[NG];
  __shared__ int    slab[NG];
  __shared__ int    svalid[NG];

  // has_valid via ballot (wave 0 covers tid 0..63 == all NG slots)
  int gv = (tid < NG) ? gmask[b * NG + tid] : 0;
  unsigned long long bal = __ballot(gv != 0);  // valid in wave 0

  // reduce batch's per-wave top3 triples
  float t0 = -INFINITY, t1 = -INFINITY, t2 = -INFINITY;
  for (int i = tid; i < NBLK * NW; i += TPB) {
    const float* bt = blockTop + ((long)b * NBLK * NW + i) * 3;
    ins3(bt[0], t0, t1, t2);
    ins3(bt[1], t0, t1, t2);
    ins3(bt[2], t0, t1, t2);
  }
  wave_top3(t0, t1, t2);
  const int lane = tid & 63, wid = tid >> 6;
  if (lane == 0) { swt[wid][0] = t0; swt[wid][1] = t1; swt[wid][2] = t2; }
  __syncthreads();
  if (tid == 0) {
    float r0 = swt[0][0], r1 = swt[0][1], r2 = swt[0][2];
    #pragma unroll
    for (int w = 1; w < NW; ++w) {
      ins3(swt[w][0], r0, r1, r2);
      ins3(swt[w][1], r0, r1, r2);
      ins3(swt[w][2], r0, r1, r2);
    }
    sfb  = (!(r0 > 0.3f) && bal != 0ULL) ? 1 : 0;
    sres = r2;
  }
  // stage gt into LDS (overlaps the decision barrier)
  if (tid < NG) {
    float4 g = gt[b * NG + tid];
    if (!gv) g = make_float4(0.f, 0.f, 0.f, 0.f);
    sbox[tid]   = g;
    sarea[tid]  = (g.z - g.x) * (g.w - g.y);
    slab[tid]   = glab[b * NG + tid];
    svalid[tid] = gv;
  }
  __syncthreads();
  if (sfb == 0) return;        // uniform exit (no barriers after this)
  const float minio = sres;

  const int a = blockIdx.x * TPB + tid;
  if (a >= NA) return;

  float4 p  = pd[(long)b * NA + a];
  float  a2 = (p.z - p.x) * (p.w - p.y);
  float best = -1.f;
  int   bidx = 0;
  #pragma unroll 8
  for (int g = 0; g < NG; ++g) {
    float4 gb = sbox[g];
    float iw = fminf(gb.z, p.z) - fmaxf(gb.x, p.x);
    float ih = fminf(gb.w, p.w) - fmaxf(gb.y, p.y);
    iw = fmaxf(iw, 0.f);
    ih = fmaxf(ih, 0.f);
    float inter = iw * ih;
    float den   = sarea[g] + a2 - inter + 1e-9f;
    float iou   = inter / den;
    bidx = (iou > best) ? g : bidx;
    best = fmaxf(best, iou);
  }
  // fallback fg: max over valid of overlaps >= min_iou. With zero-boxes and
  // has_valid guaranteed here, max over all g == max over valid g.
  bool fg    = best >= minio;
  bool maskv = fg && (svalid[bidx] != 0);
  int  blab  = slab[bidx];
  long ga = (long)b * NA + a;
  outL[ga] = maskv ? (float)blab : 80.f;
  float m = maskv ? 1.f : 0.f;
  float4 gb = sbox[bidx];
  outB[ga] = make_float4(gb.x * m, gb.y * m, gb.z * m, gb.w * m);
  outF[ga] = fg ? 1.f : 0.f;
  if (maskv) outS[ga * NC + blab] = 1.f;  // scores were all-zero for this batch
}

// ---------------------------------------------------------------------------
// launch
// ---------------------------------------------------------------------------
extern "C" void kernel_launch(void* const* d_in, const int* in_sizes, int n_in,
                              void* d_out, int out_size, void* d_ws, size_t ws_size,
                              hipStream_t stream) {
  // inputs (setup_inputs order): 0 pd_scores (unused), 1 pd_bboxes,
  // 2 anc_points (unused), 3 gt_labels, 4 gt_bboxes, 5 mask_gt
  const float4* pd    = (const float4*)d_in[1];
  const int*    glab  = (const int*)d_in[3];
  const float4* gt    = (const float4*)d_in[4];
  const int*    gmask = (const int*)d_in[5];

  float* outf = (float*)d_out;
  // outputs concatenated flat in return order (all as float32):
  // target_labels [16,33600], target_bboxes [16,33600,4],
  // target_scores [16,33600,80], fg_mask [16,33600], target_gt_idx [16,33600]
  float*  outL = outf;
  float4* outB = (float4*)(outf + (long)BS * NA);
  float*  outS = outf + (long)BS * NA * 5;
  float*  outF = outf + (long)BS * NA * 5 + (long)BS * NA * NC;
  float*  outI = outF + (long)BS * NA;

  // workspace: per-wave block top3 (BS*NBLK*NW*3 floats ~ 100 KB)
  float* blockTop = (float*)d_ws;

  dim3 grid(NBLK, BS);
  p1_kernel<<<grid, TPB, 0, stream>>>(pd, gt, glab, gmask,
                                      outL, outB, outS, outF, outI, blockTop);
  p3_kernel<<<grid, TPB, 0, stream>>>(pd, gt, glab, gmask, blockTop,
                                      outL, outB, outS, outF);
}